// Round 8
// baseline (313.050 us; speedup 1.0000x reference)
//
#include <hip/hip_runtime.h>
#include <hip/hip_bf16.h>

#define N_NODES 100000
#define N_FACES 200000
#define FM 32                    // faces per tile
#define ROWS 96                  // 3 variants * FM
#define NTILES (N_FACES / FM)    // 6250
#define GRID 768                 // 3 blocks/CU target
#define FS 136                   // Xff row stride (shorts)
#define ES 40                    // Xe row stride (shorts)
#define HS 136                   // H row stride (shorts)
#define W1K 160                  // w1t global k-stride
#define W2K 128                  // w2t global k-stride

typedef __attribute__((ext_vector_type(8))) short s8v;
typedef __attribute__((ext_vector_type(4))) short s4v;
typedef __attribute__((ext_vector_type(4))) float f4v;

static __device__ __forceinline__ short f2bf(float x) {
  __hip_bfloat16 h = __float2bfloat16(x);
  short s;
  __builtin_memcpy(&s, &h, 2);
  return s;
}
static __device__ __forceinline__ unsigned us(short x) {
  return (unsigned)(unsigned short)x;
}

// W1 -> bf16 w1t[n(128)][k(160)] with K-permutation:
//   k in [0,128): ff -> W1 row k+6 ; k in [128,134): edges -> W1 row k-128 ; else 0.
// W2 -> bf16 w2t[o(32)][k(128)].
__global__ __launch_bounds__(256) void prep_kernel(
    const float* __restrict__ W1, const float* __restrict__ W2,
    short* __restrict__ w1t, short* __restrict__ w2t)
{
  int t = blockIdx.x * 256 + threadIdx.x;
  if (t < 128 * W1K) {
    int n = t / W1K, k = t % W1K;
    float v = 0.f;
    if (k < 128) v = W1[(k + 6) * 128 + n];
    else if (k < 134) v = W1[(k - 128) * 128 + n];
    w1t[t] = f2bf(v);
  }
  if (t < 32 * W2K) {
    int o = t / W2K, k = t % W2K;
    w2t[t] = f2bf(W2[k * 32 + o]);
  }
}

__global__ __launch_bounds__(512, 6) void face_kernel(
    const float* __restrict__ pos, const float* __restrict__ ffeat,
    const float* __restrict__ b1, const float* __restrict__ b2,
    const int* __restrict__ faces,
    const short* __restrict__ w1t_g, const short* __restrict__ w2t_g,
    float* __restrict__ out_ff, float* __restrict__ sums, int* __restrict__ cnt)
{
  __shared__ short xff[FM * FS];     //  8704 B (single buffer: write sealed by bar1/bar2)
  __shared__ short xe[ROWS * ES];    //  7680 B (single buffer: write sealed by bar2/bar3)
  __shared__ short hbuf[ROWS * HS];  // 26112 B
  __shared__ int   fidx[2][ROWS];    //   768 B (node id, rt = floc*3+v; dbuf: read post-bar3)
  __shared__ float pvtx[ROWS * 4];   //  1536 B (xyz of vertex rt; lifetime within one iter)
  __shared__ float gsumb[FM * 30];   //  3840 B
  // total 48640 B -> 3 blocks/CU

  const int t = threadIdx.x;
  const int lane = t & 63;
  const int wv = t >> 6;             // 0..7
  const int l15 = lane & 15;
  const int lq = lane >> 4;          // 0..3
  const int kq = lq * 8;
  const int nsel = wv & 1;
  const int rt = t - 384;            // gather-lane index (waves 6..7.5)
  const bool rt96 = ((unsigned)rt < 96u);

  // ---- persistent weight fragments (registers), biases
  s8v bw1[5], bw2[4];
#pragma unroll
  for (int kc = 0; kc < 5; ++kc)
    bw1[kc] = *(const s8v*)(w1t_g + (wv * 16 + l15) * W1K + kc * 32 + kq);
#pragma unroll
  for (int kk = 0; kk < 4; ++kk)
    bw2[kk] = *(const s8v*)(w2t_g + (nsel * 16 + l15) * W2K + kk * 32 + kq);
  const float b1j = b1[wv * 16 + l15];
  const float b2o = b2[nsel * 16 + l15];

  // ---- zero xe pad cols 6..39 (once; never overwritten)
  if (t < ROWS) {
    s8v z = (s8v){0, 0, 0, 0, 0, 0, 0, 0};
    *(unsigned*)&xe[t * ES + 6] = 0u;
    *(s8v*)&xe[t * ES + 8] = z;
    *(s8v*)&xe[t * ES + 16] = z;
    *(s8v*)&xe[t * ES + 24] = z;
    *(s8v*)&xe[t * ES + 32] = z;
  }

  // ---- prologue: stage tile0 (ff + faces coalesced + own-vertex pos)
  int fvn = 0;  // faces value for tile i+1 (own (face,vertex) node id)
  {
    int fb = blockIdx.x * FM;
    const float* fp = ffeat + ((size_t)(fb + (t >> 4)) << 7) + ((t & 15) << 3);
    f4v v0 = *(const f4v*)fp, v1 = *(const f4v*)(fp + 4);
    s8v s;
    s[0] = f2bf(v0.x); s[1] = f2bf(v0.y); s[2] = f2bf(v0.z); s[3] = f2bf(v0.w);
    s[4] = f2bf(v1.x); s[5] = f2bf(v1.y); s[6] = f2bf(v1.z); s[7] = f2bf(v1.w);
    *(s8v*)&xff[(t >> 4) * FS + ((t & 15) << 3)] = s;
    if (rt96) {
      int id = faces[fb * 3 + rt];       // coalesced: 96 consecutive dwords
      fidx[0][rt] = id;
      pvtx[rt * 4 + 0] = pos[id * 3 + 0];
      pvtx[rt * 4 + 1] = pos[id * 3 + 1];
      pvtx[rt * 4 + 2] = pos[id * 3 + 2];
      if (blockIdx.x + GRID < NTILES)
        fvn = faces[(fb + GRID * FM) * 3 + rt];
    }
  }
  __syncthreads();
  // ---- build tile0 edges from LDS pvtx
  if (rt96) {
    int floc = rt / 3, v = rt - floc * 3;
    int rb = floc * 3 + (v == 2 ? 0 : v + 1);
    int rc = floc * 3 + (v == 0 ? 2 : v - 1);
    float ax = pvtx[rt * 4], ay = pvtx[rt * 4 + 1], az = pvtx[rt * 4 + 2];
    float bx = pvtx[rb * 4], by = pvtx[rb * 4 + 1], bz = pvtx[rb * 4 + 2];
    float cx = pvtx[rc * 4], cy = pvtx[rc * 4 + 1], cz = pvtx[rc * 4 + 2];
    int r_ = v * 32 + floc;
    s4v e;
    e[0] = f2bf(bx - ax); e[1] = f2bf(by - ay); e[2] = f2bf(bz - az); e[3] = f2bf(cx - ax);
    *(s4v*)&xe[r_ * ES] = e;
    *(unsigned*)&xe[r_ * ES + 4] = us(f2bf(cy - ay)) | (us(f2bf(cz - az)) << 16);
  }
  __syncthreads();

  int iter = 0;
  for (int tile = blockIdx.x; tile < NTILES; tile += GRID, ++iter) {
    const int cur = iter & 1, nxt = cur ^ 1;
    const int fb_c = tile * FM;
    const int tile_n = tile + GRID;
    const bool hn = tile_n < NTILES;
    const bool hn2 = tile_n + GRID < NTILES;

    // ---- top: issue ALL next-tile global loads (drain merges at bar1)
    f4v nv0, nv1;
    float npx = 0.f, npy = 0.f, npz = 0.f;
    int fvn2 = 0;
    if (hn) {
      const float* fp = ffeat + ((size_t)(tile_n * FM + (t >> 4)) << 7) + ((t & 15) << 3);
      nv0 = *(const f4v*)fp;
      nv1 = *(const f4v*)(fp + 4);
      if (rt96) {  // own-vertex pos gather (node id prefetched 2 tiles ahead)
        npx = pos[fvn * 3 + 0]; npy = pos[fvn * 3 + 1]; npz = pos[fvn * 3 + 2];
      }
    }
    if (hn2 && rt96) fvn2 = faces[(tile_n + GRID) * FM * 3 + rt];

    // ---- GEMM1: (96 x 160) @ (160 x 16-per-wave)
    f4v acc1[6];
#pragma unroll
    for (int m = 0; m < 6; ++m) acc1[m] = (f4v){0.f, 0.f, 0.f, 0.f};
#pragma unroll
    for (int kc = 0; kc < 4; ++kc) {
      s8v a0 = *(const s8v*)&xff[l15 * FS + kc * 32 + kq];
      s8v a1 = *(const s8v*)&xff[(16 + l15) * FS + kc * 32 + kq];
      acc1[0] = __builtin_amdgcn_mfma_f32_16x16x32_bf16(a0, bw1[kc], acc1[0], 0, 0, 0);
      acc1[1] = __builtin_amdgcn_mfma_f32_16x16x32_bf16(a1, bw1[kc], acc1[1], 0, 0, 0);
      acc1[2] = __builtin_amdgcn_mfma_f32_16x16x32_bf16(a0, bw1[kc], acc1[2], 0, 0, 0);
      acc1[3] = __builtin_amdgcn_mfma_f32_16x16x32_bf16(a1, bw1[kc], acc1[3], 0, 0, 0);
      acc1[4] = __builtin_amdgcn_mfma_f32_16x16x32_bf16(a0, bw1[kc], acc1[4], 0, 0, 0);
      acc1[5] = __builtin_amdgcn_mfma_f32_16x16x32_bf16(a1, bw1[kc], acc1[5], 0, 0, 0);
    }
#pragma unroll
    for (int m = 0; m < 6; ++m) {
      s8v a = *(const s8v*)&xe[(m * 16 + l15) * ES + kq];
      acc1[m] = __builtin_amdgcn_mfma_f32_16x16x32_bf16(a, bw1[4], acc1[m], 0, 0, 0);
    }

    __syncthreads();  // bar1: the ONE vmem drain point (loads + prev stores/atomics)

    // ---- epi1: H write; zero gsumb; stage xff/pvtx/fidx for tile i+1
    {
      int j = wv * 16 + l15;
#pragma unroll
      for (int m = 0; m < 6; ++m)
#pragma unroll
        for (int r = 0; r < 4; ++r)
          hbuf[(m * 16 + lq * 4 + r) * HS + j] = f2bf(fmaxf(acc1[m][r] + b1j, 0.f));
    }
    for (int e = t; e < FM * 30; e += 512) gsumb[e] = 0.f;
    if (hn) {
      s8v s;
      s[0] = f2bf(nv0.x); s[1] = f2bf(nv0.y); s[2] = f2bf(nv0.z); s[3] = f2bf(nv0.w);
      s[4] = f2bf(nv1.x); s[5] = f2bf(nv1.y); s[6] = f2bf(nv1.z); s[7] = f2bf(nv1.w);
      *(s8v*)&xff[(t >> 4) * FS + ((t & 15) << 3)] = s;
      if (rt96) {
        pvtx[rt * 4 + 0] = npx; pvtx[rt * 4 + 1] = npy; pvtx[rt * 4 + 2] = npz;
        fidx[nxt][rt] = fvn;
      }
    }
    __syncthreads();  // bar2: lgkm only

    // ---- GEMM2 (c2 kept in regs) + gsumb LDS atomics + edge build (i+1)
    f4v c2a = (f4v){0.f, 0.f, 0.f, 0.f}, c2b = (f4v){0.f, 0.f, 0.f, 0.f};
    const int m0 = wv >> 1, m1 = (wv >> 1) + 4;
#pragma unroll
    for (int kk = 0; kk < 4; ++kk) {
      s8v a = *(const s8v*)&hbuf[(m0 * 16 + l15) * HS + kk * 32 + kq];
      c2a = __builtin_amdgcn_mfma_f32_16x16x32_bf16(a, bw2[kk], c2a, 0, 0, 0);
    }
    if (wv < 4) {
#pragma unroll
      for (int kk = 0; kk < 4; ++kk) {
        s8v a = *(const s8v*)&hbuf[(m1 * 16 + l15) * HS + kk * 32 + kq];
        c2b = __builtin_amdgcn_mfma_f32_16x16x32_bf16(a, bw2[kk], c2b, 0, 0, 0);
      }
    }
    const int o = nsel * 16 + l15;
    if (o >= 3) {
#pragma unroll
      for (int r = 0; r < 4; ++r)
        atomicAdd(&gsumb[((m0 * 16 + lq * 4 + r) & 31) * 30 + (o - 3)], c2a[r] + b2o);
      if (wv < 4) {
#pragma unroll
        for (int r = 0; r < 4; ++r)
          atomicAdd(&gsumb[((m1 * 16 + lq * 4 + r) & 31) * 30 + (o - 3)], c2b[r] + b2o);
      }
    }
    if (hn && rt96) {
      int floc = rt / 3, v = rt - floc * 3;
      int rb = floc * 3 + (v == 2 ? 0 : v + 1);
      int rc = floc * 3 + (v == 0 ? 2 : v - 1);
      float ax = pvtx[rt * 4], ay = pvtx[rt * 4 + 1], az = pvtx[rt * 4 + 2];
      float bx = pvtx[rb * 4], by = pvtx[rb * 4 + 1], bz = pvtx[rb * 4 + 2];
      float cx = pvtx[rc * 4], cy = pvtx[rc * 4 + 1], cz = pvtx[rc * 4 + 2];
      int r_ = v * 32 + floc;
      s4v e;
      e[0] = f2bf(bx - ax); e[1] = f2bf(by - ay); e[2] = f2bf(bz - az); e[3] = f2bf(cx - ax);
      *(s4v*)&xe[r_ * ES] = e;
      *(unsigned*)&xe[r_ * ES + 4] = us(f2bf(cy - ay)) | (us(f2bf(cz - az)) << 16);
    }
    __syncthreads();  // bar3: lgkm only

    // ---- post: out_ff write + DEFERRED global atomics (retire at next bar1)
    for (int e = t; e < FM * 29; e += 512) {
      int floc = e / 29, c = e - floc * 29;
      out_ff[((size_t)(fb_c + floc)) * 29 + c] = gsumb[floc * 30 + c] * (1.0f / 3.0f);
    }
    if (o < 3) {
#pragma unroll
      for (int r = 0; r < 4; ++r) {
        int row = m0 * 16 + lq * 4 + r;
        int nid = fidx[cur][(row & 31) * 3 + (row >> 5)];
        atomicAdd(&sums[nid * 3 + o], c2a[r] + b2o);
        if (o == 0) atomicAdd(&cnt[nid], 1);
      }
      if (wv < 4) {
#pragma unroll
        for (int r = 0; r < 4; ++r) {
          int row = m1 * 16 + lq * 4 + r;
          int nid = fidx[cur][(row & 31) * 3 + (row >> 5)];
          atomicAdd(&sums[nid * 3 + o], c2b[r] + b2o);
          if (o == 0) atomicAdd(&cnt[nid], 1);
        }
      }
    }
    fvn = fvn2;
  }
}

__global__ __launch_bounds__(256) void node_kernel(
    const float* __restrict__ pos, const float* __restrict__ sums,
    const int* __restrict__ cnt, float* __restrict__ out)
{
  int n = blockIdx.x * 256 + threadIdx.x;
  if (n >= N_NODES) return;
  float c = fmaxf((float)cnt[n], 1.0f);
#pragma unroll
  for (int o = 0; o < 3; ++o) {
    float d = sums[n * 3 + o] / c;
    out[n * 3 + o] = d;
    out[3 * N_NODES + n * 3 + o] = pos[n * 3 + o] + d;
  }
}

extern "C" void kernel_launch(void* const* d_in, const int* in_sizes, int n_in,
                              void* d_out, int out_size, void* d_ws, size_t ws_size,
                              hipStream_t stream) {
  const float* pos   = (const float*)d_in[0];
  const float* ffeat = (const float*)d_in[1];
  const float* W1    = (const float*)d_in[2];
  const float* b1    = (const float*)d_in[3];
  const float* W2    = (const float*)d_in[4];
  const float* b2    = (const float*)d_in[5];
  const int*   faces = (const int*)d_in[6];
  float* out = (float*)d_out;

  float* sums = (float*)d_ws;                  // 300000 f32
  int*   cnt  = (int*)(sums + 3 * N_NODES);    // 100000 i32
  short* w1t  = (short*)(cnt + N_NODES);       // 128*160 bf16
  short* w2t  = w1t + 128 * W1K;               // 32*128 bf16

  hipMemsetAsync(d_ws, 0, (size_t)(3 * N_NODES + N_NODES) * 4, stream);
  prep_kernel<<<80, 256, 0, stream>>>(W1, W2, w1t, w2t);
  face_kernel<<<GRID, 512, 0, stream>>>(pos, ffeat, b1, b2, faces, w1t, w2t,
                                        out + 6 * N_NODES, sums, cnt);
  node_kernel<<<(N_NODES + 255) / 256, 256, 0, stream>>>(pos, sums, cnt, out);
}